// Round 1
// baseline (283.473 us; speedup 1.0000x reference)
//
#include <hip/hip_runtime.h>

#define SEQ 2048
#define HDIM 64
#define NH 16
#define EMB 1024

typedef __attribute__((ext_vector_type(8))) short bf16x8;
typedef __attribute__((ext_vector_type(4))) float f32x4;

static __device__ __forceinline__ unsigned short f2bf(float f) {
  unsigned int u = __builtin_bit_cast(unsigned int, f);
  u += 0x7FFF + ((u >> 16) & 1);  // round-to-nearest-even
  return (unsigned short)(u >> 16);
}

// ---------------- fp32 -> bf16 convert (vectorized) ----------------
__global__ void cvt_bf16(const float* __restrict__ in, unsigned short* __restrict__ out, int n) {
  int i = (blockIdx.x * blockDim.x + threadIdx.x) * 4;
  if (i + 3 < n) {
    float4 v = *(const float4*)(in + i);
    ushort4 o;
    o.x = f2bf(v.x); o.y = f2bf(v.y); o.z = f2bf(v.z); o.w = f2bf(v.w);
    *(ushort4*)(out + i) = o;
  }
}

// ---------------- QKV projection GEMM (m97-style 128x128 tile) ----------------
// out[m,n] = sum_k x[m,k] * W[n,k]  (+ bias[n]),  both operands K-contiguous.
// z = 0:Q, 1:K  -> [BH][S][64];  z = 2:V -> transposed [BH][64][S]
__global__ __launch_bounds__(256) void qkv_gemm(
    const unsigned short* __restrict__ xb,
    const unsigned short* __restrict__ wb,   // [3][1024][1024]
    const float* __restrict__ bq, const float* __restrict__ bk, const float* __restrict__ bv,
    unsigned short* __restrict__ qout, unsigned short* __restrict__ kout,
    unsigned short* __restrict__ vtout)
{
  __shared__ unsigned short As[128 * 32];
  __shared__ unsigned short Bs[128 * 32];
  const int z = blockIdx.z;
  const unsigned short* Bw = wb + (size_t)z * (EMB * EMB);
  const int tid = threadIdx.x;
  const int w = tid >> 6, l = tid & 63;
  const int wr = w >> 1, wc = w & 1;
  const int m0 = blockIdx.x * 128, n0 = blockIdx.y * 128;
  const int lc = l & 15, lg = l >> 4;

  f32x4 acc[4][4] = {};

  for (int kb = 0; kb < EMB; kb += 32) {
    // stage A,B tiles (128x32 bf16 each) via global_load_lds width=16
    for (int c = 0; c < 2; ++c) {
      int elem = c * 2048 + w * 512 + l * 8;   // element idx in [128][32] tile
      int row = elem >> 5, col = elem & 31;
      __builtin_amdgcn_global_load_lds(
          (const __attribute__((address_space(1))) void*)(xb + (size_t)(m0 + row) * EMB + kb + col),
          (__attribute__((address_space(3))) void*)(As + c * 2048 + w * 512), 16, 0, 0);
      __builtin_amdgcn_global_load_lds(
          (const __attribute__((address_space(1))) void*)(Bw + (size_t)(n0 + row) * EMB + kb + col),
          (__attribute__((address_space(3))) void*)(Bs + c * 2048 + w * 512), 16, 0, 0);
    }
    __syncthreads();
    bf16x8 am[4], bn[4];
    for (int i = 0; i < 4; ++i) {
      am[i] = *(const bf16x8*)(As + (wr * 64 + i * 16 + lc) * 32 + lg * 8);
      bn[i] = *(const bf16x8*)(Bs + (wc * 64 + i * 16 + lc) * 32 + lg * 8);
    }
    for (int i = 0; i < 4; ++i)
      for (int j = 0; j < 4; ++j)
        acc[i][j] = __builtin_amdgcn_mfma_f32_16x16x32_bf16(am[i], bn[j], acc[i][j], 0, 0, 0);
    __syncthreads();
  }

  const float* bias = (z == 0) ? bq : (z == 1) ? bk : bv;
  for (int i = 0; i < 4; ++i)
    for (int j = 0; j < 4; ++j)
      for (int r = 0; r < 4; ++r) {
        int m = m0 + wr * 64 + i * 16 + lg * 4 + r;      // row = (lane>>4)*4+reg
        int n = n0 + wc * 64 + j * 16 + lc;              // col = lane&15
        float v = acc[i][j][r] + bias[n];
        unsigned short o16 = f2bf(v);
        int b = m >> 11, s = m & 2047, h = n >> 6, d = n & 63;
        if (z == 2)
          vtout[(((size_t)b * NH + h) * HDIM + d) * SEQ + s] = o16;
        else {
          unsigned short* dst = (z == 0) ? qout : kout;
          dst[(((size_t)b * NH + h) * SEQ + s) * HDIM + d] = o16;
        }
      }
}

// ---------------- flash attention, 4 waves/block, 16 q-rows/wave ----------------
__global__ __launch_bounds__(256) void attn(
    const unsigned short* __restrict__ Q,   // [BH][S][64]
    const unsigned short* __restrict__ K,   // [BH][S][64]
    const unsigned short* __restrict__ VT,  // [BH][64][S]
    float* __restrict__ out)                // [B][S][1024]
{
  __shared__ unsigned short plds[4][16 * 32];   // per-wave P tile
  const int bh = blockIdx.y, b = bh >> 4, h = bh & 15;
  const int w = threadIdx.x >> 6, l = threadIdx.x & 63;
  const int lc = l & 15, lg = l >> 4;
  const int q0 = blockIdx.x * 64 + w * 16;
  const unsigned short* Qp = Q + ((size_t)bh * SEQ + q0) * HDIM;
  const unsigned short* Kp = K + (size_t)bh * SEQ * HDIM;
  const unsigned short* Vp = VT + (size_t)bh * HDIM * SEQ;

  bf16x8 qf[2];
  for (int dc = 0; dc < 2; ++dc)
    qf[dc] = *(const bf16x8*)(Qp + lc * HDIM + dc * 32 + lg * 8);

  f32x4 o[4] = {};
  float m_run[4], l_run[4];
  for (int r = 0; r < 4; ++r) { m_run[r] = -1e30f; l_run[r] = 0.f; }
  unsigned short* pw = plds[w];
  const float scale = 0.03125f;   // 1/sqrt(1024)  (note: embed_dim, not head_dim)

  for (int kb = 0; kb < SEQ; kb += 32) {
    // --- QK^T: 16q x 32k tile ---
    bf16x8 kf[2][2];
    for (int kc = 0; kc < 2; ++kc)
      for (int dc = 0; dc < 2; ++dc)
        kf[kc][dc] = *(const bf16x8*)(Kp + (size_t)(kb + kc * 16 + lc) * HDIM + dc * 32 + lg * 8);
    f32x4 sc[2] = {};
    for (int dc = 0; dc < 2; ++dc) {
      sc[0] = __builtin_amdgcn_mfma_f32_16x16x32_bf16(qf[dc], kf[0][dc], sc[0], 0, 0, 0);
      sc[1] = __builtin_amdgcn_mfma_f32_16x16x32_bf16(qf[dc], kf[1][dc], sc[1], 0, 0, 0);
    }
    // --- scale + corner mask + row max ---
    float t[2][4], mx[4];
    for (int r = 0; r < 4; ++r) {
      int q = q0 + lg * 4 + r;
      mx[r] = -1e30f;
      for (int kc = 0; kc < 2; ++kc) {
        int key = kb + kc * 16 + lc;
        float v = sc[kc][r] * scale;
        bool masked = (q < 8 && key < 8) || (q >= SEQ - 8 && key >= SEQ - 8);
        v = masked ? -1e30f : v;
        t[kc][r] = v;
        mx[r] = fmaxf(mx[r], v);
      }
    }
    for (int off = 1; off < 16; off <<= 1)
      for (int r = 0; r < 4; ++r)
        mx[r] = fmaxf(mx[r], __shfl_xor(mx[r], off));
    // --- online softmax update ---
    float p[2][4], rs[4], sfr[4];
    for (int r = 0; r < 4; ++r) {
      float mn = fmaxf(m_run[r], mx[r]);
      sfr[r] = __expf(m_run[r] - mn);
      m_run[r] = mn;
      rs[r] = 0.f;
      for (int kc = 0; kc < 2; ++kc) {
        float e = __expf(t[kc][r] - mn);
        p[kc][r] = e;
        rs[r] += e;
      }
    }
    for (int off = 1; off < 16; off <<= 1)
      for (int r = 0; r < 4; ++r)
        rs[r] += __shfl_xor(rs[r], off);
    for (int r = 0; r < 4; ++r)
      l_run[r] = l_run[r] * sfr[r] + rs[r];
    for (int db = 0; db < 4; ++db)
      for (int r = 0; r < 4; ++r)
        o[db][r] *= sfr[r];
    // --- P (C-layout) -> LDS -> A-layout fragment ---
    for (int kc = 0; kc < 2; ++kc)
      for (int r = 0; r < 4; ++r)
        pw[(lg * 4 + r) * 32 + kc * 16 + lc] = f2bf(p[kc][r]);
    bf16x8 pa = *(const bf16x8*)(pw + lc * 32 + lg * 8);
    // --- PV: accumulate 16q x 64d ---
    for (int db = 0; db < 4; ++db) {
      bf16x8 vf = *(const bf16x8*)(Vp + (size_t)(db * 16 + lc) * SEQ + kb + lg * 8);
      o[db] = __builtin_amdgcn_mfma_f32_16x16x32_bf16(pa, vf, o[db], 0, 0, 0);
    }
  }
  // --- epilogue: O / l ---
  for (int db = 0; db < 4; ++db)
    for (int r = 0; r < 4; ++r) {
      int q = q0 + lg * 4 + r;
      int d = db * 16 + lc;
      out[((size_t)b * SEQ + q) * EMB + h * HDIM + d] = o[db][r] / l_run[r];
    }
}

extern "C" void kernel_launch(void* const* d_in, const int* in_sizes, int n_in,
                              void* d_out, int out_size, void* d_ws, size_t ws_size,
                              hipStream_t stream) {
  const float* x  = (const float*)d_in[0];
  const float* Wq = (const float*)d_in[1];
  const float* bq = (const float*)d_in[2];
  const float* Wk = (const float*)d_in[3];
  const float* bk = (const float*)d_in[4];
  const float* Wv = (const float*)d_in[5];
  const float* bv = (const float*)d_in[6];
  // d_in[7] = global_bias: per-head scalar added uniformly over key axis -> softmax-invariant, dropped.
  float* out = (float*)d_out;

  char* ws = (char*)d_ws;
  unsigned short* xb   = (unsigned short*)(ws);                 //  8 MB: x bf16 [4096][1024]
  unsigned short* wb   = (unsigned short*)(ws + (8u  << 20));   //  6 MB: Wq|Wk|Wv bf16
  unsigned short* qb   = (unsigned short*)(ws + (14u << 20));   //  8 MB: Q [BH][S][64]
  unsigned short* kbuf = (unsigned short*)(ws + (22u << 20));   //  8 MB: K [BH][S][64]
  unsigned short* vtb  = (unsigned short*)(ws + (30u << 20));   //  8 MB: V^T [BH][64][S]

  cvt_bf16<<<4096, 256, 0, stream>>>(x, xb, 2 * SEQ * EMB);
  cvt_bf16<<<1024, 256, 0, stream>>>(Wq, wb, EMB * EMB);
  cvt_bf16<<<1024, 256, 0, stream>>>(Wk, wb + EMB * EMB, EMB * EMB);
  cvt_bf16<<<1024, 256, 0, stream>>>(Wv, wb + 2 * EMB * EMB, EMB * EMB);
  qkv_gemm<<<dim3(32, 8, 3), 256, 0, stream>>>(xb, wb, bq, bk, bv, qb, kbuf, vtb);
  attn<<<dim3(SEQ / 64, 32), 256, 0, stream>>>(qb, kbuf, vtb, out);
}

// Round 3
// 174.487 us; speedup vs baseline: 1.6246x; 1.6246x over previous
//
#include <hip/hip_runtime.h>

#define SEQ 2048
#define HDIM 64
#define NH 16
#define EMB 1024

typedef __attribute__((ext_vector_type(8))) short bf16x8;
typedef __attribute__((ext_vector_type(4))) float f32x4;
typedef __attribute__((ext_vector_type(16))) float f32x16;

static __device__ __forceinline__ unsigned short f2bf(float f) {
  unsigned int u = __builtin_bit_cast(unsigned int, f);
  u += 0x7FFF + ((u >> 16) & 1);  // round-to-nearest-even
  return (unsigned short)(u >> 16);
}

// ---------------- fp32 -> bf16 convert (vectorized) ----------------
__global__ void cvt_bf16(const float* __restrict__ in, unsigned short* __restrict__ out, int n) {
  int i = (blockIdx.x * blockDim.x + threadIdx.x) * 4;
  if (i + 3 < n) {
    float4 v = *(const float4*)(in + i);
    ushort4 o;
    o.x = f2bf(v.x); o.y = f2bf(v.y); o.z = f2bf(v.z); o.w = f2bf(v.w);
    *(ushort4*)(out + i) = o;
  }
}

// ---------------- QKV projection GEMM (m97-style 128x128 tile) ----------------
__global__ __launch_bounds__(256) void qkv_gemm(
    const unsigned short* __restrict__ xb,
    const unsigned short* __restrict__ wb,   // [3][1024][1024]
    const float* __restrict__ bq, const float* __restrict__ bk, const float* __restrict__ bv,
    unsigned short* __restrict__ qout, unsigned short* __restrict__ kout,
    unsigned short* __restrict__ vtout)
{
  __shared__ unsigned short As[128 * 32];
  __shared__ unsigned short Bs[128 * 32];
  const int z = blockIdx.z;
  const unsigned short* Bw = wb + (size_t)z * (EMB * EMB);
  const int tid = threadIdx.x;
  const int w = tid >> 6, l = tid & 63;
  const int wr = w >> 1, wc = w & 1;
  const int m0 = blockIdx.x * 128, n0 = blockIdx.y * 128;
  const int lc = l & 15, lg = l >> 4;

  f32x4 acc[4][4] = {};

  for (int kb = 0; kb < EMB; kb += 32) {
    for (int c = 0; c < 2; ++c) {
      int elem = c * 2048 + w * 512 + l * 8;
      int row = elem >> 5, col = elem & 31;
      __builtin_amdgcn_global_load_lds(
          (const __attribute__((address_space(1))) void*)(xb + (size_t)(m0 + row) * EMB + kb + col),
          (__attribute__((address_space(3))) void*)(As + c * 2048 + w * 512), 16, 0, 0);
      __builtin_amdgcn_global_load_lds(
          (const __attribute__((address_space(1))) void*)(Bw + (size_t)(n0 + row) * EMB + kb + col),
          (__attribute__((address_space(3))) void*)(Bs + c * 2048 + w * 512), 16, 0, 0);
    }
    __syncthreads();
    bf16x8 am[4], bn[4];
    for (int i = 0; i < 4; ++i) {
      am[i] = *(const bf16x8*)(As + (wr * 64 + i * 16 + lc) * 32 + lg * 8);
      bn[i] = *(const bf16x8*)(Bs + (wc * 64 + i * 16 + lc) * 32 + lg * 8);
    }
    for (int i = 0; i < 4; ++i)
      for (int j = 0; j < 4; ++j)
        acc[i][j] = __builtin_amdgcn_mfma_f32_16x16x32_bf16(am[i], bn[j], acc[i][j], 0, 0, 0);
    __syncthreads();
  }

  const float* bias = (z == 0) ? bq : (z == 1) ? bk : bv;
  for (int i = 0; i < 4; ++i)
    for (int j = 0; j < 4; ++j)
      for (int r = 0; r < 4; ++r) {
        int m = m0 + wr * 64 + i * 16 + lg * 4 + r;
        int n = n0 + wc * 64 + j * 16 + lc;
        float v = acc[i][j][r] + bias[n];
        unsigned short o16 = f2bf(v);
        int b = m >> 11, s = m & 2047, h = n >> 6, d = n & 63;
        if (z == 2)
          vtout[(((size_t)b * NH + h) * HDIM + d) * SEQ + s] = o16;
        else {
          unsigned short* dst = (z == 0) ? qout : kout;
          dst[(((size_t)b * NH + h) * SEQ + s) * HDIM + d] = o16;
        }
      }
}

// ---------------- flash attention, swapped-QK^T, in-register softmax ----------------
// 1 wave per block, 32 q-rows per wave, 32 keys per iteration, zero LDS.
// QK^T: D = K·Q^T (32x32x16 MFMA) -> lane holds P^T[k][q=lane&31], k=(reg&3)+8*(reg>>2)+4*(lane>>5)
// PV:   O^T = V^T·P^T            -> lane holds O^T[d][q=lane&31]
// All cross-half moves via __shfl_xor(.,32) (semantics-certain), no permlane/perm.
__global__ __launch_bounds__(64) void attn(
    const unsigned short* __restrict__ Q,   // [BH][S][64]
    const unsigned short* __restrict__ K,   // [BH][S][64]
    const unsigned short* __restrict__ VT,  // [BH][64][S]
    float* __restrict__ out)                // [B][S][1024]
{
  // XCD-aware mapping: all 64 q-tiles of a head on one XCD (4 heads x 512KB = 2MB/XCD L2)
  const int g = blockIdx.x;
  const int xcd = g & 7, j0 = g >> 3;
  const int bh = xcd * 4 + (j0 >> 6);
  const int tile = j0 & 63;
  const int b = bh >> 4, h = bh & 15;
  const int l = threadIdx.x;
  const int q = l & 31;       // q within tile AND row index for K/V A-fragments
  const int hh = l >> 5;
  const int q0 = tile * 32;

  const unsigned short* Qp = Q + ((size_t)bh * SEQ + q0) * HDIM;
  const unsigned short* Kp = K + (size_t)bh * SEQ * HDIM;
  const unsigned short* Vp = VT + (size_t)bh * HDIM * SEQ;

  bf16x8 qf[4];   // Q as B-operand: B[k=d][col=q], d = 16c + hh*8 + j
#pragma unroll
  for (int c = 0; c < 4; ++c)
    qf[c] = *(const bf16x8*)(Qp + q * HDIM + c * 16 + hh * 8);

  f32x16 oa = {}, ob = {};        // O^T d=0..31 / d=32..63
  float ml = -1e30f, lr = 0.f;    // running max (log2 domain) and denom
  const float C1 = 0.03125f * 1.44269504f;   // scale * log2(e)
  const float THR = 8.f * 1.44269504f;       // defer-max threshold (8 nats)
  const bool mask_head = (tile == 0), mask_tail = (tile == 63);

  bf16x8 k0f[4], v0f[4], k1f[4], v1f[4];

  auto loadK = [&](bf16x8* dst, int kbase) {   // A[row=key=l&31][k=d=16c+hh*8+j]
#pragma unroll
    for (int c = 0; c < 4; ++c)
      dst[c] = *(const bf16x8*)(Kp + (size_t)(kbase + q) * HDIM + c * 16 + hh * 8);
  };
  auto loadV = [&](bf16x8* dst, int kbase) {   // A[row=d_local][k=key_local]
#pragma unroll
    for (int dt = 0; dt < 2; ++dt)
#pragma unroll
      for (int c = 0; c < 2; ++c)
        dst[dt * 2 + c] = *(const bf16x8*)(Vp + (size_t)(dt * 32 + q) * SEQ + kbase + c * 16 + hh * 8);
  };

  auto body = [&](const bf16x8* kf, const bf16x8* vf, int kb) {
    f32x16 s = {};
#pragma unroll
    for (int c = 0; c < 4; ++c)
      s = __builtin_amdgcn_mfma_f32_32x32x16_bf16(kf[c], qf[c], s, 0, 0, 0);
    // corner mask: keys 0..7 are regs 0..3; keys 24..31 (of last block) are regs 12..15
    if (mask_head && kb == 0 && q < 8) {
      s[0] = -1e30f; s[1] = -1e30f; s[2] = -1e30f; s[3] = -1e30f;
    }
    if (mask_tail && kb == SEQ - 32 && q >= 24) {
      s[12] = -1e30f; s[13] = -1e30f; s[14] = -1e30f; s[15] = -1e30f;
    }
    // tile max: in-register tree + one cross-half shuffle
    float t0 = fmaxf(fmaxf(s[0], s[1]), fmaxf(s[2], s[3]));
    float t1 = fmaxf(fmaxf(s[4], s[5]), fmaxf(s[6], s[7]));
    float t2 = fmaxf(fmaxf(s[8], s[9]), fmaxf(s[10], s[11]));
    float t3 = fmaxf(fmaxf(s[12], s[13]), fmaxf(s[14], s[15]));
    float mr = fmaxf(fmaxf(t0, t1), fmaxf(t2, t3));
    mr = fmaxf(mr, __shfl_xor(mr, 32));
    float pml = mr * C1;
    // defer-max: rescale only when tile max exceeds running max by >8 nats (rare)
    if (!__all(pml - ml <= THR)) {
      float mln = fmaxf(ml, pml);
      float sf = __builtin_amdgcn_exp2f(ml - mln);
#pragma unroll
      for (int jj = 0; jj < 16; ++jj) { oa[jj] *= sf; ob[jj] *= sf; }
      lr *= sf; ml = mln;
    }
    float e[16];
#pragma unroll
    for (int jj = 0; jj < 16; ++jj)
      e[jj] = __builtin_amdgcn_exp2f(s[jj] * C1 - ml);
    float r = (((e[0] + e[1]) + (e[2] + e[3])) + ((e[4] + e[5]) + (e[6] + e[7]))) +
              (((e[8] + e[9]) + (e[10] + e[11])) + ((e[12] + e[13]) + (e[14] + e[15])));
    r += __shfl_xor(r, 32);
    lr += r;
    // pack p -> bf16 pairs, explicit RNE, low half = even key
    unsigned int P[8];
#pragma unroll
    for (int jj = 0; jj < 8; ++jj) {
      unsigned int ua = __builtin_bit_cast(unsigned int, e[2 * jj]);
      ua += 0x7FFFu + ((ua >> 16) & 1);
      unsigned int ub = __builtin_bit_cast(unsigned int, e[2 * jj + 1]);
      ub += 0x7FFFu + ((ub >> 16) & 1);
      P[jj] = (ua >> 16) | (ub & 0xFFFF0000u);
    }
    // redistribute C-layout key-pairs -> B-fragment words via shfl_xor(32).
    // pair (Pa has keys X@hh0/X+4@hh1, Pb has X+8@hh0/X+12@hh1):
    //   w1 = {Pa_lo | Pb_lo},  w2 = {Pa_hi | Pb_hi}
    unsigned int W0[4], W1[4];
    auto xchg = [&](unsigned int Pa, unsigned int Pb, unsigned int& w1, unsigned int& w2) {
      unsigned int sel = hh ? Pa : Pb;
      unsigned int y = (unsigned int)__shfl_xor((int)sel, 32);
      w1 = hh ? y : Pa;   // lo halves of both
      w2 = hh ? Pb : y;   // hi halves of both
    };
    xchg(P[0], P[2], W0[0], W0[2]);
    xchg(P[1], P[3], W0[1], W0[3]);
    xchg(P[4], P[6], W1[0], W1[2]);
    xchg(P[5], P[7], W1[1], W1[3]);
    uint4 u0q = make_uint4(W0[0], W0[1], W0[2], W0[3]);  // B[k=0..15][q]
    uint4 u1q = make_uint4(W1[0], W1[1], W1[2], W1[3]);  // B[k=16..31][q]
    bf16x8 pb0 = __builtin_bit_cast(bf16x8, u0q);
    bf16x8 pb1 = __builtin_bit_cast(bf16x8, u1q);
    oa = __builtin_amdgcn_mfma_f32_32x32x16_bf16(vf[0], pb0, oa, 0, 0, 0);
    oa = __builtin_amdgcn_mfma_f32_32x32x16_bf16(vf[1], pb1, oa, 0, 0, 0);
    ob = __builtin_amdgcn_mfma_f32_32x32x16_bf16(vf[2], pb0, ob, 0, 0, 0);
    ob = __builtin_amdgcn_mfma_f32_32x32x16_bf16(vf[3], pb1, ob, 0, 0, 0);
  };

  loadK(k0f, 0); loadV(v0f, 0);
  for (int kb = 0; kb < SEQ; kb += 64) {
    loadK(k1f, kb + 32); loadV(v1f, kb + 32);      // prefetch next block
    body(k0f, v0f, kb);
    if (kb + 64 < SEQ) { loadK(k0f, kb + 64); loadV(v0f, kb + 64); }
    body(k1f, v1f, kb + 32);
  }

  float inv = __builtin_amdgcn_rcpf(lr);
  float* outp = out + ((size_t)b * SEQ + q0 + q) * EMB + h * HDIM;
#pragma unroll
  for (int qd = 0; qd < 4; ++qd) {   // regs 4qd..4qd+3 -> d = 8qd + 4hh + 0..3
    float4 sa = {oa[4 * qd] * inv, oa[4 * qd + 1] * inv, oa[4 * qd + 2] * inv, oa[4 * qd + 3] * inv};
    *(float4*)(outp + 8 * qd + 4 * hh) = sa;
    float4 sb = {ob[4 * qd] * inv, ob[4 * qd + 1] * inv, ob[4 * qd + 2] * inv, ob[4 * qd + 3] * inv};
    *(float4*)(outp + 32 + 8 * qd + 4 * hh) = sb;
  }
}

extern "C" void kernel_launch(void* const* d_in, const int* in_sizes, int n_in,
                              void* d_out, int out_size, void* d_ws, size_t ws_size,
                              hipStream_t stream) {
  const float* x  = (const float*)d_in[0];
  const float* Wq = (const float*)d_in[1];
  const float* bq = (const float*)d_in[2];
  const float* Wk = (const float*)d_in[3];
  const float* bk = (const float*)d_in[4];
  const float* Wv = (const float*)d_in[5];
  const float* bv = (const float*)d_in[6];
  // d_in[7] = global_bias: per-head scalar, uniform over key axis -> softmax-invariant, dropped.
  float* out = (float*)d_out;

  char* ws = (char*)d_ws;
  unsigned short* xb   = (unsigned short*)(ws);
  unsigned short* wb   = (unsigned short*)(ws + (8u  << 20));
  unsigned short* qb   = (unsigned short*)(ws + (14u << 20));
  unsigned short* kbuf = (unsigned short*)(ws + (22u << 20));
  unsigned short* vtb  = (unsigned short*)(ws + (30u << 20));

  cvt_bf16<<<4096, 256, 0, stream>>>(x, xb, 2 * SEQ * EMB);
  cvt_bf16<<<1024, 256, 0, stream>>>(Wq, wb, EMB * EMB);
  cvt_bf16<<<1024, 256, 0, stream>>>(Wk, wb + EMB * EMB, EMB * EMB);
  cvt_bf16<<<1024, 256, 0, stream>>>(Wv, wb + 2 * EMB * EMB, EMB * EMB);
  qkv_gemm<<<dim3(32, 8, 3), 256, 0, stream>>>(xb, wb, bq, bk, bv, qb, kbuf, vtb);
  attn<<<dim3(2048), 64, 0, stream>>>(qb, kbuf, vtb, out);
}